// Round 3
// baseline (3313.223 us; speedup 1.0000x reference)
//
#include <hip/hip_runtime.h>

// Q4_0 SwiGLU FFN, MI355X (gfx950). dim=4096, hidden=11008, M=4096 tokens.
// R3: f16 pipeline, perm-based nibble->f16 dequant, double-buffered LDS with
// one barrier/iter + 1-iter W-register prefetch, XOR-swizzled B tile, XCD
// block swizzle.

typedef _Float16 f16;
typedef _Float16 f16x2 __attribute__((ext_vector_type(2)));
typedef _Float16 f16x4 __attribute__((ext_vector_type(4)));
typedef _Float16 f16x8 __attribute__((ext_vector_type(8)));
typedef float    f32x4 __attribute__((ext_vector_type(4)));
typedef unsigned int uint;
typedef uint u32x2 __attribute__((ext_vector_type(2)));
typedef uint u32x4 __attribute__((ext_vector_type(4)));

#define BM 128
#define BN 128
#define BK 32

__device__ __forceinline__ void gload_lds16(const f16* g, f16* l) {
  __builtin_amdgcn_global_load_lds(
      (__attribute__((address_space(1))) void*)(g),
      (__attribute__((address_space(3))) void*)(l), 16, 0, 0);
}

// ------------------------------------------------------------- x -> f16 ----
__global__ void f32_to_f16_k(const float* __restrict__ x,
                             f16* __restrict__ y, int n4) {
  int t = blockIdx.x * blockDim.x + threadIdx.x;
  if (t >= n4) return;
  float4 v = ((const float4*)x)[t];
  f16x4 o = {(f16)v.x, (f16)v.y, (f16)v.z, (f16)v.w};
  ((f16x4*)y)[t] = o;
}

// ---- dequant 4 int32-packed bytes -> 4 f16 weights (one nibble kind) ------
// nibble u' = ((byte>>sh)&0xF)^8 ; f16(0x6400|u') = 1024+u' exact;
// (1024+u' - 1032) exact = u'-8 = signed value; then *scale (1 f16 rounding).
__device__ __forceinline__ u32x2 dq4(int4 q, uint sh, f16x2 sc2) {
  uint c = __builtin_amdgcn_perm((uint)q.y, (uint)q.x, 0x0C0C0400u)
         | __builtin_amdgcn_perm((uint)q.w, (uint)q.z, 0x04000C0Cu);
  uint nib = ((c >> sh) & 0x0F0F0F0Fu) ^ 0x08080808u;
  uint p01 = __builtin_amdgcn_perm(0x64646464u, nib, 0x04010400u);
  uint p23 = __builtin_amdgcn_perm(0x64646464u, nib, 0x04030402u);
  f16x2 v01 = __builtin_bit_cast(f16x2, p01);
  f16x2 v23 = __builtin_bit_cast(f16x2, p23);
  const f16x2 bias = {(f16)(-1032.0f), (f16)(-1032.0f)};
  v01 = (v01 + bias) * sc2;
  v23 = (v23 + bias) * sc2;
  u32x2 r = {__builtin_bit_cast(uint, v01), __builtin_bit_cast(uint, v23)};
  return r;
}

// ------------------------------------------------ dequant-fused GEMM (B^T) --
// C(MxN) = A(MxK) * W(NxK)^T. W packed Q4_0 (one byte per int32).
// EPI: 0 = f32 store, 1 = f16 store, 2 = G = silu(acc)*G in place.
template <int EPI>
__launch_bounds__(256)
__global__ void gemm_dq_k(const f16* __restrict__ A,
                          const int* __restrict__ Wq,
                          const float* __restrict__ S,
                          f16* __restrict__ G,
                          float* __restrict__ Fout,
                          int M, int N, int K) {
  __shared__ __attribute__((aligned(16))) f16 As[2][BM * BK];  // 2 x 8 KB
  __shared__ __attribute__((aligned(16))) f16 Bs[2][BN * BK];  // 2 x 8 KB

  const int tid  = threadIdx.x;
  const int lane = tid & 63;
  const int wave = tid >> 6;

  // XCD-friendly swizzle: 8 consecutive blocks = 8 m-tiles, same n-tile.
  const int NBn = N >> 7;
  const int bpg = NBn << 3;
  const int g   = blockIdx.x / bpg;
  const int r   = blockIdx.x % bpg;
  const int m0  = (g * 8 + (r & 7)) * BM;
  const int n0  = (r >> 3) * BN;

  // --- A staging (async DMA, 2 x 16B per thread)
  const int o0 = tid * 16, o1 = o0 + 4096;
  const f16* a0 = A + (size_t)(m0 + (o0 >> 6)) * K + ((o0 & 63) >> 1);
  const f16* a1 = A + (size_t)(m0 + (o1 >> 6)) * K + ((o1 & 63) >> 1);
  const int lA0 = o0 >> 1, lA1 = o1 >> 1;

  // --- B dequant staging: thread -> (row rr, 16-elem k-segment h)
  const int rr = tid >> 1;
  const int h  = tid & 1;
  const int* wrow   = Wq + (size_t)(n0 + rr) * (K >> 1);
  const float* srow = S + (size_t)(n0 + rr) * (K >> 6);
  const int swz = (rr >> 1) & 3;                    // 16B-unit xor swizzle
  const int e0 = rr * BK + (((2 * h)     ^ swz) << 3);
  const int e1 = rr * BK + (((2 * h + 1) ^ swz) << 3);

  // --- fragment offsets (hoisted)
  const int fm = lane & 15, fq = lane >> 4;
  const int wm = (wave >> 1) * 64, wn = (wave & 1) * 64;
  int aoff[4], boff[4];
#pragma unroll
  for (int i = 0; i < 4; i++) aoff[i] = (wm + 16 * i + fm) * BK + fq * 8;
#pragma unroll
  for (int j = 0; j < 4; j++) {
    int rj = wn + 16 * j + fm;
    boff[j] = rj * BK + ((fq ^ ((rj >> 1) & 3)) << 3);
  }

  f32x4 acc[4][4] = {};

  // ---- prologue: stage tile 0 into buf 0; prefetch W regs for tile 1.
  gload_lds16(a0, &As[0][lA0]);
  gload_lds16(a1, &As[0][lA1]);
  {
    const int kk = 16 * h;  // tile 0
    const int4* wp = (const int4*)(wrow + ((kk >> 7) << 6) + (kk & 63));
    int4 p0 = wp[0], p1 = wp[1], p2 = wp[2], p3 = wp[3];
    f16 s_ = (f16)srow[kk >> 6];
    f16x2 sc2 = {s_, s_};
    u32x2 d0 = dq4(p0, 4u, sc2), d1 = dq4(p1, 4u, sc2);
    u32x2 d2 = dq4(p2, 4u, sc2), d3 = dq4(p3, 4u, sc2);
    u32x4 lo = {d0.x, d0.y, d1.x, d1.y};
    u32x4 hi = {d2.x, d2.y, d3.x, d3.y};
    *(u32x4*)&Bs[0][e0] = lo;
    *(u32x4*)&Bs[0][e1] = hi;
  }
  int4 q0, q1, q2, q3;
  float sf;
  {
    const int kk = BK + 16 * h;  // tile 1 (K >= 64 always)
    const int4* wp = (const int4*)(wrow + ((kk >> 7) << 6) + (kk & 63));
    q0 = wp[0]; q1 = wp[1]; q2 = wp[2]; q3 = wp[3];
    sf = srow[kk >> 6];
  }
  __syncthreads();

  // ---- main loop: one barrier per iteration.
  for (int k0 = 0, i = 0; k0 < K; k0 += BK, ++i) {
    const int cur = i & 1, nxt = cur ^ 1;
    const bool more  = (k0 + BK) < K;
    const bool more2 = (k0 + 2 * BK) < K;

    if (more) {
      a0 += BK; a1 += BK;
      gload_lds16(a0, &As[nxt][lA0]);
      gload_lds16(a1, &As[nxt][lA1]);
      const uint sh = (((k0 + BK) & 127) < 64) ? 4u : 0u;
      f16 s_ = (f16)sf;
      f16x2 sc2 = {s_, s_};
      u32x2 d0 = dq4(q0, sh, sc2), d1 = dq4(q1, sh, sc2);
      u32x2 d2 = dq4(q2, sh, sc2), d3 = dq4(q3, sh, sc2);
      u32x4 lo = {d0.x, d0.y, d1.x, d1.y};
      u32x4 hi = {d2.x, d2.y, d3.x, d3.y};
      *(u32x4*)&Bs[nxt][e0] = lo;
      *(u32x4*)&Bs[nxt][e1] = hi;
    }
    if (more2) {  // prefetch W regs for tile i+2
      const int kk = k0 + 2 * BK + 16 * h;
      const int4* wp = (const int4*)(wrow + ((kk >> 7) << 6) + (kk & 63));
      q0 = wp[0]; q1 = wp[1]; q2 = wp[2]; q3 = wp[3];
      sf = srow[kk >> 6];
    }

    f16x8 af[4], bf[4];
#pragma unroll
    for (int t = 0; t < 4; t++) af[t] = *(const f16x8*)&As[cur][aoff[t]];
#pragma unroll
    for (int t = 0; t < 4; t++) bf[t] = *(const f16x8*)&Bs[cur][boff[t]];
#pragma unroll
    for (int ii = 0; ii < 4; ii++)
#pragma unroll
      for (int jj = 0; jj < 4; jj++)
        acc[ii][jj] = __builtin_amdgcn_mfma_f32_16x16x32_f16(
            af[ii], bf[jj], acc[ii][jj], 0, 0, 0);

    if (more) __syncthreads();
  }

  // ---- epilogue. C/D layout: col = lane&15, row = fq*4 + reg.
#pragma unroll
  for (int ii = 0; ii < 4; ii++) {
    const int row0 = m0 + wm + 16 * ii + fq * 4;
#pragma unroll
    for (int jj = 0; jj < 4; jj++) {
      const int col = n0 + wn + 16 * jj + fm;
#pragma unroll
      for (int rg = 0; rg < 4; rg++) {
        size_t idx = (size_t)(row0 + rg) * N + col;
        if constexpr (EPI == 0) {
          Fout[idx] = acc[ii][jj][rg];
        } else if constexpr (EPI == 1) {
          G[idx] = (f16)acc[ii][jj][rg];
        } else {
          float a = acc[ii][jj][rg];
          float gg = (float)G[idx];
          G[idx] = (f16)((a / (1.0f + __expf(-a))) * gg);
        }
      }
    }
  }
}

// ------------------------------------------------------------------ launch --
extern "C" void kernel_launch(void* const* d_in, const int* in_sizes, int n_in,
                              void* d_out, int out_size, void* d_ws,
                              size_t ws_size, hipStream_t stream) {
  const float* x  = (const float*)d_in[0];
  const int*   w1 = (const int*)d_in[1];
  const float* s1 = (const float*)d_in[2];
  const int*   w2 = (const int*)d_in[3];
  const float* s2 = (const float*)d_in[4];
  const int*   w3 = (const int*)d_in[5];
  const float* s3 = (const float*)d_in[6];
  float* out = (float*)d_out;

  const int dim = 4096, hidden = 11008;
  const int M = in_sizes[0] / dim;  // 4096

  // workspace: Xb (33.5 MB) + G (90.2 MB) = 123.7 MB
  char* ws = (char*)d_ws;
  f16* Xb = (f16*)ws;
  f16* G  = (f16*)(ws + (size_t)M * dim * 2);

  const int nx4 = M * dim / 4;
  f32_to_f16_k<<<(nx4 + 255) / 256, 256, 0, stream>>>(x, Xb, nx4);

  const int nbh = (hidden / BN) * (M / BM);  // 2752
  // G = X * W3^T
  gemm_dq_k<1><<<nbh, 256, 0, stream>>>(Xb, w3, s3, G, nullptr, M, hidden, dim);
  // G = silu(X * W1^T) * G   (in place)
  gemm_dq_k<2><<<nbh, 256, 0, stream>>>(Xb, w1, s1, G, nullptr, M, hidden, dim);

  const int nbo = (dim / BN) * (M / BM);     // 1024
  // out = G * W2^T (f32)
  gemm_dq_k<0><<<nbo, 256, 0, stream>>>(G, w2, s2, nullptr, out, M, dim, hidden);
}